// Round 8
// baseline (100.953 us; speedup 1.0000x reference)
//
#include <hip/hip_runtime.h>
#include <math.h>

typedef __attribute__((ext_vector_type(8))) short short8;
typedef __attribute__((ext_vector_type(16))) float f32x16;

#define GLOBAL_AS __attribute__((address_space(1)))
#define LDS_AS __attribute__((address_space(3)))

__device__ inline short f2bf(float f) {
    unsigned u = __float_as_uint(f);
    u += 0x7FFFu + ((u >> 16) & 1u);   // RNE to bf16
    return (short)(u >> 16);
}

// ------ Kernel 1: cast centers (f32->bf16) + chalf[k] = 0.5*sum(c^2) in f32 ------
__global__ __launch_bounds__(256) void cast_centers_kernel(const float* __restrict__ c,
                                                           short* __restrict__ cb,
                                                           float* __restrict__ chalf, int dim) {
    int k = blockIdx.x;
    int t = threadIdx.x;
    const float* row = c + (size_t)k * dim;
    short* orow = cb + (size_t)k * dim;
    float s = 0.f;
    for (int i = t * 4; i < dim; i += blockDim.x * 4) {
        float4 v = *(const float4*)(row + i);
        s += v.x * v.x + v.y * v.y + v.z * v.z + v.w * v.w;
        short4 o;
        o.x = f2bf(v.x); o.y = f2bf(v.y); o.z = f2bf(v.z); o.w = f2bf(v.w);
        *(short4*)(orow + i) = o;
    }
#pragma unroll
    for (int off = 32; off; off >>= 1) s += __shfl_xor(s, off);
    __shared__ float red[4];
    if ((t & 63) == 0) red[t >> 6] = s;
    __syncthreads();
    if (t == 0) chalf[k] = 0.5f * (red[0] + red[1] + red[2] + red[3]);
}

// ------------- Kernel 2: fused GEMM (64 x FULL-ROW 1024) + log-softmax epilogue -------------
// logits[b,k] = x_b . c_k - 0.5*||c_k||^2  (row-constant -0.5*||x||^2 cancels in log_softmax)
// out[b,k] = logits[b,k] - logsumexp_k(logits[b,:])
//
// mfma_f32_32x32x16_bf16, UK=16 K-units, ring-4 LDS (B 4x32KB + A 4x2KB), depth-3
// prefetch with counted vmcnt(10) (T4). ONE barrier per unit (ring-4 ordering makes the
// second barrier unnecessary: slot written at unit u was last read at unit u-3, >=2
// barriers upstream with lgkm drained). 32-B LDS rows make every wave64 frag read a
// contiguous 1024-B span -> ZERO bank conflicts, no swizzle needed anywhere.
// A: x read once as f32 (float2/thread/unit) -> cvt bf16 -> ds_write one unit ahead.
// B: centers bf16 via global_load_lds (linear dest = linear source).
#define UK 16
#define BBASE 8192     // A ring: 4 x 2048 at 0; B ring: 4 x 32768 at 8192
#define SCR 139264     // epilogue scratch

__global__ __launch_bounds__(512, 2) void fused_kernel(
    const float* __restrict__ x,     // [M][K] f32
    const short* __restrict__ cb,    // [N][K] bf16
    const float* __restrict__ chalf, // [N]
    float* __restrict__ out,         // [M][N]
    int M, int N, int K) {
    __shared__ char lds[143872];
    const int t = threadIdx.x;
    const int l = t & 63, w = t >> 6, l31 = l & 31, hi2 = l >> 5;
    const int brow = blockIdx.x * 64;
    const size_t rowbB = (size_t)K * 2;      // centers row stride (bytes)
    const int NT = K / UK;                   // 64 units

    // ---- fragment-read offsets (32-B rows; 64 lanes cover 1024 contiguous B) ----
    const int aro = l31 * 32 + hi2 * 16;             // + m*1024 + slot*2048
    const int bro = w * 4096 + l31 * 32 + hi2 * 16;  // + n*1024 + BBASE + slot*32768

    // ---- B staging: thread t, GLD j -> center row j*256 + (t>>1), 16B chunk t&1 ----
    const char* bsrc = (const char*)cb + (size_t)(t >> 1) * rowbB + (t & 1) * 16;
    const size_t bjs = 256 * rowbB;

    // ---- A staging: thread t -> x row t>>3, f32 col pair (t&7)*2 ----
    const float* xsrc = x + (size_t)(brow + (t >> 3)) * K + (t & 7) * 2;
    const int awofs = (t >> 3) * 32 + (t & 7) * 4;   // + slot*2048

#define GLD(gp, lo) __builtin_amdgcn_global_load_lds((const GLOBAL_AS int*)(gp), \
                        (LDS_AS int*)(lds + (lo)), 16, 0, 0)
#define STAGEB(uu, sl) do {                                                      \
    _Pragma("unroll")                                                            \
    for (int j = 0; j < 4; ++j)                                                  \
        GLD(bsrc + (size_t)j * bjs + (size_t)(uu) * (UK * 2),                    \
            BBASE + (sl) * 32768 + j * 8192 + t * 16);                           \
    } while (0)
#define AWRITE(sl, fv) do {                                                      \
    unsigned p_ = ((unsigned)(unsigned short)f2bf((fv).y) << 16) |               \
                  (unsigned)(unsigned short)f2bf((fv).x);                        \
    *(unsigned*)(lds + (sl) * 2048 + awofs) = p_; } while (0)

    f32x16 acc[2][4];
#pragma unroll
    for (int m = 0; m < 2; ++m)
#pragma unroll
        for (int n = 0; n < 4; ++n)
#pragma unroll
            for (int q = 0; q < 16; ++q) acc[m][n][q] = 0.f;

    // ---- prologue: stage units 0..2, A(0) written, F(1),F(2) in regs ----
    float2 f1, f2;
    {
        float2 g0 = *(const float2*)(xsrc);
        f1 = *(const float2*)(xsrc + UK);
        f2 = *(const float2*)(xsrc + 2 * UK);
        STAGEB(0, 0); STAGEB(1, 1); STAGEB(2, 2);
        AWRITE(0, g0);
        asm volatile("s_waitcnt vmcnt(8)" ::: "memory");   // unit 0 B landed (+F's retired)
        asm volatile("s_waitcnt lgkmcnt(0)" ::: "memory"); // A(0) visible
    }
    __builtin_amdgcn_s_barrier();
    __builtin_amdgcn_sched_barrier(0);

    for (int u = 0; u < NT; ++u) {
        const int sl = u & 3;
        short8 af[2], bf[4];
#pragma unroll
        for (int m = 0; m < 2; ++m)
            af[m] = *(const short8*)(lds + sl * 2048 + m * 1024 + aro);
#pragma unroll
        for (int n = 0; n < 4; ++n)
            bf[n] = *(const short8*)(lds + BBASE + sl * 32768 + n * 1024 + bro);
        float2 fn = f2;
        if (u + 3 < NT) {
            STAGEB(u + 3, (u + 3) & 3);
            fn = *(const float2*)(xsrc + (size_t)(u + 3) * UK);
        }
        if (u + 1 < NT) {
            AWRITE((u + 1) & 3, f1);
            f1 = f2; f2 = fn;
        }
        __builtin_amdgcn_sched_barrier(0);
        __builtin_amdgcn_s_setprio(1);
#pragma unroll
        for (int m = 0; m < 2; ++m)
#pragma unroll
            for (int n = 0; n < 4; ++n)
                acc[m][n] = __builtin_amdgcn_mfma_f32_32x32x16_bf16(af[m], bf[n], acc[m][n], 0, 0, 0);
        __builtin_amdgcn_s_setprio(0);
        __builtin_amdgcn_sched_barrier(0);
        if (u <= NT - 4)      { asm volatile("s_waitcnt vmcnt(10)" ::: "memory"); }
        else if (u == NT - 3) { asm volatile("s_waitcnt vmcnt(5)" ::: "memory"); }
        else if (u == NT - 2) { asm volatile("s_waitcnt vmcnt(0)" ::: "memory"); }
        asm volatile("s_waitcnt lgkmcnt(0)" ::: "memory");
        __builtin_amdgcn_sched_barrier(0);
        __builtin_amdgcn_s_barrier();
        __builtin_amdgcn_sched_barrier(0);
    }

    // ================= fused log-softmax epilogue =================
    // 32x32 C/D layout [m74/m101]: col = lane&31, row = (q&3) + 8*(q>>2) + 4*(lane>>5).
    // Lane holds rows R = m*32 + (q&3) + 8*(q>>2) + 4*hi2, cols w*128 + n*32 + l31.
    float ch[4];
#pragma unroll
    for (int n = 0; n < 4; ++n) ch[n] = chalf[w * 128 + n * 32 + l31];

    // pass 1: per-lane max over n, all-reduce over the 32-lane half, cross-wave via LDS
    {
        float pm[2][16];
#pragma unroll
        for (int m = 0; m < 2; ++m)
#pragma unroll
            for (int q = 0; q < 16; ++q) {
                float v = acc[m][0][q] - ch[0];
#pragma unroll
                for (int n = 1; n < 4; ++n) v = fmaxf(v, acc[m][n][q] - ch[n]);
                pm[m][q] = v;
            }
#pragma unroll
        for (int d = 1; d <= 16; d <<= 1)
#pragma unroll
            for (int m = 0; m < 2; ++m)
#pragma unroll
                for (int q = 0; q < 16; ++q) pm[m][q] = fmaxf(pm[m][q], __shfl_xor(pm[m][q], d));
        if (l31 == 0) {
#pragma unroll
            for (int m = 0; m < 2; ++m)
#pragma unroll
                for (int q = 0; q < 16; ++q) {
                    const int R = m * 32 + (q & 3) + 8 * (q >> 2) + 4 * hi2;
                    *(float*)(lds + SCR + R * 32 + w * 4) = pm[m][q];   // wred[R][w]
                }
        }
    }
    __syncthreads();
    if (t < 64) {
        float4 a = *(const float4*)(lds + SCR + t * 32);
        float4 b = *(const float4*)(lds + SCR + t * 32 + 16);
        float g = fmaxf(fmaxf(fmaxf(a.x, a.y), fmaxf(a.z, a.w)),
                        fmaxf(fmaxf(b.x, b.y), fmaxf(b.z, b.w)));
        *(float*)(lds + SCR + 2048 + t * 4) = g;                        // gmax[R]
    }
    __syncthreads();

    // pass 2: sum of exp
    {
        float ps[2][16];
#pragma unroll
        for (int m = 0; m < 2; ++m)
#pragma unroll
            for (int q = 0; q < 16; ++q) {
                const int R = m * 32 + (q & 3) + 8 * (q >> 2) + 4 * hi2;
                const float g = *(const float*)(lds + SCR + 2048 + R * 4);
                float s = 0.f;
#pragma unroll
                for (int n = 0; n < 4; ++n) s += __expf(acc[m][n][q] - ch[n] - g);
                ps[m][q] = s;
            }
#pragma unroll
        for (int d = 1; d <= 16; d <<= 1)
#pragma unroll
            for (int m = 0; m < 2; ++m)
#pragma unroll
                for (int q = 0; q < 16; ++q) ps[m][q] += __shfl_xor(ps[m][q], d);
        if (l31 == 0) {
#pragma unroll
            for (int m = 0; m < 2; ++m)
#pragma unroll
                for (int q = 0; q < 16; ++q) {
                    const int R = m * 32 + (q & 3) + 8 * (q >> 2) + 4 * hi2;
                    *(float*)(lds + SCR + R * 32 + w * 4) = ps[m][q];   // wred[R][w] (reused)
                }
        }
    }
    __syncthreads();
    if (t < 64) {
        float4 a = *(const float4*)(lds + SCR + t * 32);
        float4 b = *(const float4*)(lds + SCR + t * 32 + 16);
        float s = (a.x + a.y + a.z + a.w) + (b.x + b.y + b.z + b.w);
        *(float*)(lds + SCR + 2304 + t * 4) =
            *(const float*)(lds + SCR + 2048 + t * 4) + __logf(s);      // lse[R]
    }
    __syncthreads();

    // write final output (lanes l31 consecutive -> 128-B coalesced segments)
#pragma unroll
    for (int m = 0; m < 2; ++m)
#pragma unroll
        for (int q = 0; q < 16; ++q) {
            const int R = m * 32 + (q & 3) + 8 * (q >> 2) + 4 * hi2;
            const float lse = *(const float*)(lds + SCR + 2304 + R * 4);
            float* orow = out + (size_t)(brow + R) * N + w * 128 + l31;
#pragma unroll
            for (int n = 0; n < 4; ++n)
                orow[n * 32] = acc[m][n][q] - ch[n] - lse;
        }
#undef STAGEB
#undef AWRITE
#undef GLD
}

extern "C" void kernel_launch(void* const* d_in, const int* in_sizes, int n_in,
                              void* d_out, int out_size, void* d_ws, size_t ws_size,
                              hipStream_t stream) {
    const float* x = (const float*)d_in[0];
    const float* c = (const float*)d_in[1];
    float* out = (float*)d_out;

    int dim = (int)(sqrt((double)in_sizes[1]) + 0.5);   // 1024
    int batch = in_sizes[0] / dim;                      // 16384

    // workspace layout: [centers bf16][chalf f32]
    size_t cb_bytes = (size_t)dim * dim * 2;
    short* cb = (short*)d_ws;
    float* chalf = (float*)((char*)d_ws + cb_bytes);

    cast_centers_kernel<<<dim, 256, 0, stream>>>(c, cb, chalf, dim);

    fused_kernel<<<batch / 64, 512, 0, stream>>>(x, cb, chalf, out, batch, dim, dim);
}

// Round 9
// 57.385 us; speedup vs baseline: 1.7592x; 1.7592x over previous
//
#include <hip/hip_runtime.h>
#include <math.h>

typedef __attribute__((ext_vector_type(8))) short short8;
typedef __attribute__((ext_vector_type(4))) float f32x4;

__device__ inline short f2bf(float f) {
    unsigned u = __float_as_uint(f);
    u += 0x7FFFu + ((u >> 16) & 1u);   // RNE to bf16
    return (short)(u >> 16);
}

// ---- Kernel 1: centers f32 [N][K] -> cbF in MFMA-fragment order + chalf ----
// cbF layout: [kstep][ntile][lane][16B]; lane = (n&15) + ((k>>3)&3)*16,
// frag bytes = k&7 (8 consecutive k per lane). Slab per kstep = (N/16)*1024 B.
// One block per center row n, 128 threads: thread i handles k = i*8..i*8+7.
__global__ __launch_bounds__(128) void cast_centers_frag(const float* __restrict__ c,
                                                         short* __restrict__ cbF,
                                                         float* __restrict__ chalf, int K) {
    const int n = blockIdx.x;
    const int i = threadIdx.x;
    const int k0 = i * 8;
    const float* row = c + (size_t)n * K;
    float4 a = *(const float4*)(row + k0);
    float4 b = *(const float4*)(row + k0 + 4);
    float s = a.x * a.x + a.y * a.y + a.z * a.z + a.w * a.w +
              b.x * b.x + b.y * b.y + b.z * b.z + b.w * b.w;
    short8 o;
    o[0] = f2bf(a.x); o[1] = f2bf(a.y); o[2] = f2bf(a.z); o[3] = f2bf(a.w);
    o[4] = f2bf(b.x); o[5] = f2bf(b.y); o[6] = f2bf(b.z); o[7] = f2bf(b.w);
    const size_t slab = (size_t)(K / 16) * 1024;          // bytes per kstep slab (N==K here)
    const size_t addr = (size_t)(k0 >> 5) * slab + (size_t)(n >> 4) * 1024 +
                        (size_t)((n & 15) + ((k0 >> 3) & 3) * 16) * 16;
    *(short8*)((char*)cbF + addr) = o;
#pragma unroll
    for (int off = 32; off; off >>= 1) s += __shfl_xor(s, off);
    __shared__ float red[2];
    if ((i & 63) == 0) red[i >> 6] = s;
    __syncthreads();
    if (i == 0) chalf[n] = 0.5f * (red[0] + red[1]);
}

// ------------- Kernel 2: fused GEMM (64 x FULL-ROW 1024) + log-softmax epilogue -------------
// logits[b,k] = x_b . c_k - 0.5*||c_k||^2  (row-constant -0.5*||x||^2 cancels in log_softmax)
// out[b,k] = logits[b,k] - logsumexp_k(logits[b,:])
//
// BARRIER-FREE K-loop: A (64x1024 bf16) converted once in the prologue to fragment-order
// LDS [kstep][m][lane][16B] (128 KB, read-only after one syncthreads; every frag read is a
// contiguous 1-KB wave64 span -> conflict-free). B comes from cbF (fragment-order global):
// each wave's 8 B-frag loads are contiguous 1-KB global_load_dwordx4 streams (L2-resident,
// disjoint per wave). No LDS staging, no barriers, no manual waitcnt: 8 free-running waves
// hide each other's L2 latency under MFMA. Ping-pong B registers, peeled tail.
#define SCR 131072

__global__ __launch_bounds__(512, 2) void fused_kernel(
    const float* __restrict__ x,     // [M][K] f32
    const short* __restrict__ cbF,   // fragment-order centers
    const float* __restrict__ chalf, // [N]
    float* __restrict__ out,         // [M][N]
    int M, int N, int K) {
    __shared__ char lds[131072 + 4608];
    const int t = threadIdx.x;
    const int l = t & 63, w = t >> 6, lr = l & 15, hi = l >> 4;
    const int brow = blockIdx.x * 64;

    // ---------- prologue: A f32 -> bf16, fragment order ----------
    {
        const int ar = t >> 3;                 // row 0..63
        const int cb8 = (t & 7) * 4;           // f32 col base
        const float* xrow = x + (size_t)(brow + ar) * K;
        const int mb = (ar >> 4) * 1024 + (ar & 15) * 16;   // m*1024 + lr*16
#pragma unroll
        for (int j = 0; j < 32; ++j) {
            const int k0 = cb8 + j * 32;
            float4 v = *(const float4*)(xrow + k0);
            short4 p;
            p.x = f2bf(v.x); p.y = f2bf(v.y); p.z = f2bf(v.z); p.w = f2bf(v.w);
            *(short4*)(lds + (k0 >> 5) * 4096 + mb + (((k0 >> 3) & 3) << 8) + (k0 & 7) * 2) = p;
        }
    }
    __syncthreads();

    // ---------- barrier-free K-loop ----------
    const char* bbase = (const char*)cbF + w * 8192 + l * 16;  // wave's ntile block
    const int KS = K / 32;                                     // 32 ksteps

    f32x4 acc[4][8];
#pragma unroll
    for (int m = 0; m < 4; ++m)
#pragma unroll
        for (int n = 0; n < 8; ++n)
#pragma unroll
            for (int q = 0; q < 4; ++q) acc[m][n][q] = 0.f;

#define LDB(dst, ks) do { _Pragma("unroll")                                      \
    for (int j = 0; j < 8; ++j)                                                  \
        dst[j] = *(const short8*)(bbase + (size_t)(ks) * 65536 + j * 1024); } while (0)

#define STEP(bset, ks) do {                                                      \
    short8 afr[4];                                                               \
    _Pragma("unroll")                                                            \
    for (int m = 0; m < 4; ++m)                                                  \
        afr[m] = *(const short8*)(lds + (ks) * 4096 + m * 1024 + l * 16);        \
    __builtin_amdgcn_s_setprio(1);                                               \
    _Pragma("unroll")                                                            \
    for (int m = 0; m < 4; ++m)                                                  \
        _Pragma("unroll")                                                        \
        for (int n = 0; n < 8; ++n)                                              \
            acc[m][n] = __builtin_amdgcn_mfma_f32_16x16x32_bf16(afr[m], bset[n], \
                                                                acc[m][n], 0, 0, 0); \
    __builtin_amdgcn_s_setprio(0); } while (0)

    short8 bE[8], bO[8];
    LDB(bE, 0);
    for (int k2 = 0; k2 < 15; ++k2) {
        LDB(bO, 2 * k2 + 1);
        STEP(bE, 2 * k2);
        LDB(bE, 2 * k2 + 2);
        STEP(bO, 2 * k2 + 1);
    }
    LDB(bO, 31);
    STEP(bE, 30);
    STEP(bO, 31);
#undef LDB
#undef STEP

    // ================= fused log-softmax epilogue =================
    // C/D frag layout: col = lane&15, row = (lane>>4)*4 + q.
    // Lane holds rows R = m*16 + hi*4 + q, cols w*128 + n*16 + lr.
    float ch[8];
#pragma unroll
    for (int n = 0; n < 8; ++n) ch[n] = chalf[w * 128 + n * 16 + lr];

    // pass 1: per-lane max over n, reduce over lr-lanes, cross-wave via LDS scratch
    float pm[4][4];
#pragma unroll
    for (int m = 0; m < 4; ++m)
#pragma unroll
        for (int q = 0; q < 4; ++q) {
            float v = acc[m][0][q] - ch[0];
#pragma unroll
            for (int n = 1; n < 8; ++n) v = fmaxf(v, acc[m][n][q] - ch[n]);
            pm[m][q] = v;
        }
#pragma unroll
    for (int d = 1; d <= 8; d <<= 1)
#pragma unroll
        for (int m = 0; m < 4; ++m)
#pragma unroll
            for (int q = 0; q < 4; ++q) pm[m][q] = fmaxf(pm[m][q], __shfl_xor(pm[m][q], d));
    if (lr == 0) {
#pragma unroll
        for (int m = 0; m < 4; ++m)
#pragma unroll
            for (int q = 0; q < 4; ++q)
                *(float*)(lds + SCR + (m * 16 + hi * 4 + q) * 32 + w * 4) = pm[m][q]; // wmax[R][w]
    }
    __syncthreads();
    if (t < 64) {
        float4 a = *(const float4*)(lds + SCR + t * 32);
        float4 b = *(const float4*)(lds + SCR + t * 32 + 16);
        float g = fmaxf(fmaxf(fmaxf(a.x, a.y), fmaxf(a.z, a.w)),
                        fmaxf(fmaxf(b.x, b.y), fmaxf(b.z, b.w)));
        *(float*)(lds + SCR + 4096 + t * 4) = g;                                      // gmax[R]
    }
    __syncthreads();

    // pass 2: sum of exp
    float ps[4][4];
#pragma unroll
    for (int m = 0; m < 4; ++m)
#pragma unroll
        for (int q = 0; q < 4; ++q) {
            const float g = *(const float*)(lds + SCR + 4096 + (m * 16 + hi * 4 + q) * 4);
            float s = 0.f;
#pragma unroll
            for (int n = 0; n < 8; ++n) s += __expf(acc[m][n][q] - ch[n] - g);
            ps[m][q] = s;
        }
#pragma unroll
    for (int d = 1; d <= 8; d <<= 1)
#pragma unroll
        for (int m = 0; m < 4; ++m)
#pragma unroll
            for (int q = 0; q < 4; ++q) ps[m][q] += __shfl_xor(ps[m][q], d);
    if (lr == 0) {
#pragma unroll
        for (int m = 0; m < 4; ++m)
#pragma unroll
            for (int q = 0; q < 4; ++q)
                *(float*)(lds + SCR + 2048 + (m * 16 + hi * 4 + q) * 32 + w * 4) = ps[m][q]; // wsum[R][w]
    }
    __syncthreads();
    if (t < 64) {
        float4 a = *(const float4*)(lds + SCR + 2048 + t * 32);
        float4 b = *(const float4*)(lds + SCR + 2048 + t * 32 + 16);
        float s = (a.x + a.y + a.z + a.w) + (b.x + b.y + b.z + b.w);
        *(float*)(lds + SCR + 4352 + t * 4) =
            *(const float*)(lds + SCR + 4096 + t * 4) + __logf(s);                    // lse[R]
    }
    __syncthreads();

    // write final output
#pragma unroll
    for (int m = 0; m < 4; ++m)
#pragma unroll
        for (int q = 0; q < 4; ++q) {
            const int R = m * 16 + hi * 4 + q;
            const float lse = *(const float*)(lds + SCR + 4352 + R * 4);
            float* orow = out + (size_t)(brow + R) * N + w * 128 + lr;
#pragma unroll
            for (int n = 0; n < 8; ++n)
                orow[n * 16] = acc[m][n][q] - ch[n] - lse;
        }
}

extern "C" void kernel_launch(void* const* d_in, const int* in_sizes, int n_in,
                              void* d_out, int out_size, void* d_ws, size_t ws_size,
                              hipStream_t stream) {
    const float* x = (const float*)d_in[0];
    const float* c = (const float*)d_in[1];
    float* out = (float*)d_out;

    int dim = (int)(sqrt((double)in_sizes[1]) + 0.5);   // 1024
    int batch = in_sizes[0] / dim;                      // 16384

    // workspace layout: [cbF bf16 fragment-order][chalf f32]
    size_t cb_bytes = (size_t)dim * dim * 2;
    short* cbF = (short*)d_ws;
    float* chalf = (float*)((char*)d_ws + cb_bytes);

    cast_centers_frag<<<dim, 128, 0, stream>>>(c, cbF, chalf, dim);

    fused_kernel<<<batch / 64, 512, 0, stream>>>(x, cbF, chalf, out, batch, dim, dim);
}